// Round 1
// baseline (1316.777 us; speedup 1.0000x reference)
//
#include <hip/hip_runtime.h>

// ---------------- workspace layout (float offsets) ----------------
#define OFF_X     0          // x_flat [32][46656]
#define OFF_CUR1  1492992    // [32][1000]
#define OFF_MEM1  1524992
#define OFF_MEM2  1556992
#define OFF_MEM3  1588992
#define OFF_SPK1  1620992
#define OFF_SPK1B 1652992
#define OFF_SPK2  1684992
#define OFF_SPK3  1716992
#define OFF_Q     1748992
#define OFF_K     1780992
#define OFF_V     1812992
#define OFF_MEMR  1844992    // [32][100]
#define OFF_SPKR  1848192    // [32][100]
#define OFF_MEMO  1851392    // [32]
#define OFF_PATT  1851424    // [32][8] attention partial sums
#define OFF_CNT   1851680    // [5][4] spike counters
#define OFF_OACC  1851700    // [32]
#define OFF_SC    1851732    // total, reg
#define OFF_PART  1851744    // gemm1 partials [nchunk][32][1000]

static constexpr float kBETA  = 0.8f;
static constexpr float kTHR   = 0.5f;
static constexpr float kBETAR = 0.95f;
static constexpr float kTHRR  = 1.0f;
static constexpr float kLM    = 0.0058f;

// ---------------- init: zero all persistent state ----------------
__global__ void k_init(float* ws) {
    int idx = blockIdx.x * 256 + threadIdx.x;
    if (idx < 96000) {
        ws[OFF_MEM1 + idx] = 0.f;                 // mem1, mem2, mem3 (contiguous)
    } else {
        int j = idx - 96000;
        if (j < 6744) ws[OFF_MEMR + j] = 0.f;     // mem_r..sc (contiguous)
    }
}

// ---------------- patch embed: x = patches @ W_pe + b_pe + pos ----------------
__global__ __launch_bounds__(64) void k_patch(
    const float* __restrict__ data, const float* __restrict__ Wpe,
    const float* __restrict__ bpe, const float* __restrict__ pos,
    float* __restrict__ xf)
{
    int bp = blockIdx.x;
    int b = bp / 729, p = bp % 729;
    int pr = p / 27, pc = p % 27;
    int tid = threadIdx.x;
    __shared__ float patch[256];
    const float* db = data + (size_t)b * 50176;
    for (int c = tid; c < 256; c += 64) {
        int ph = c >> 4, pw = c & 15;
        patch[c] = db[(pr * 8 + ph) * 224 + pc * 8 + pw];
    }
    __syncthreads();
    float acc = bpe[tid] + pos[p * 64 + tid];
    for (int c = 0; c < 256; ++c)
        acc = fmaf(patch[c], Wpe[c * 64 + tid], acc);
    xf[(size_t)b * 46656 + p * 64 + tid] = acc;
}

// ---------------- big GEMM partials: cur1 += x_flat @ W1 (chunked over K) ----------------
// grid (nchunk, 2): blockIdx.y selects a 16-batch group.
// acc[16][4] = 64 VGPRs -> double the resident waves vs acc[32][4];
// grid = nchunk*2 blocks ~= 11 waves/CU at nchunk=365 (was 3.8 at 243x1).
__global__ __launch_bounds__(256) void k_gemm1_part(
    const float* __restrict__ xf, const float* __restrict__ W1,
    float* __restrict__ part, int tpc)
{
    int chunk = blockIdx.x;
    int bg = blockIdx.y;                 // batch group: batches [bg*16, bg*16+16)
    int t0 = chunk * tpc;
    int t1 = t0 + tpc; if (t1 > 729) t1 = 729;
    int tid = threadIdx.x;
    __shared__ float xs[1024];           // [16 b][64 i]
    float acc[16][4];
    #pragma unroll
    for (int b = 0; b < 16; ++b)
        #pragma unroll
        for (int j = 0; j < 4; ++j) acc[b][j] = 0.f;

    const size_t bbase = (size_t)(bg * 16) * 46656;
    for (int tt = t0; tt < t1; ++tt) {
        int i0 = tt * 64;
        __syncthreads();
        for (int l = tid; l < 1024; l += 256)
            xs[l] = xf[bbase + (size_t)(l >> 6) * 46656 + i0 + (l & 63)];
        __syncthreads();
        for (int ii4 = 0; ii4 < 16; ++ii4) {
            int i = i0 + ii4 * 4;
            float w0[4], w1v[4], w2[4], w3[4];
            #pragma unroll
            for (int j = 0; j < 4; ++j) {
                int h = tid + j * 256;
                bool ok = h < 1000;
                const float* col = W1 + (size_t)i * 1000 + (ok ? h : 0);
                w0[j]  = ok ? col[0]    : 0.f;
                w1v[j] = ok ? col[1000] : 0.f;
                w2[j]  = ok ? col[2000] : 0.f;
                w3[j]  = ok ? col[3000] : 0.f;
            }
            #pragma unroll
            for (int b = 0; b < 16; ++b) {
                float4 xv = *reinterpret_cast<const float4*>(&xs[b * 64 + ii4 * 4]);
                #pragma unroll
                for (int j = 0; j < 4; ++j) {
                    float a = acc[b][j];
                    a = fmaf(xv.x, w0[j],  a);
                    a = fmaf(xv.y, w1v[j], a);
                    a = fmaf(xv.z, w2[j],  a);
                    a = fmaf(xv.w, w3[j],  a);
                    acc[b][j] = a;
                }
            }
        }
    }
    float* pc = part + (size_t)chunk * 32000 + (size_t)(bg * 16) * 1000;
    for (int b = 0; b < 16; ++b)
        #pragma unroll
        for (int j = 0; j < 4; ++j) {
            int h = tid + j * 256;
            if (h < 1000) pc[b * 1000 + h] = acc[b][j];
        }
}

__global__ void k_gemm1_reduce(const float* __restrict__ part,
                               const float* __restrict__ b1,
                               float* __restrict__ cur1, int nchunk)
{
    int idx = blockIdx.x * 256 + threadIdx.x;
    if (idx >= 32000) return;
    int h = idx % 1000;
    float a = b1[h];
    for (int c = 0; c < nchunk; ++c) a += part[(size_t)c * 32000 + idx];
    cur1[idx] = a;
}

// ---------------- step A: double leaky on mem1 ----------------
__global__ void k_stepA(const float* __restrict__ cur1, float* __restrict__ mem1,
                        float* __restrict__ spk1, float* __restrict__ spk1b, float* cnt)
{
    int idx = blockIdx.x * 256 + threadIdx.x;
    float s1 = 0.f;
    if (idx < 32000) {
        float m = mem1[idx], c = cur1[idx];
        float r1 = (m - kTHR > 0.f) ? kTHR : 0.f;
        float ma = __fsub_rn(__fadd_rn(__fmul_rn(kBETA, m), c), r1);
        s1 = (ma - kTHR > 0.f) ? 1.f : 0.f;
        float r2 = __fmul_rn(s1, kTHR);
        float mb = __fsub_rn(__fadd_rn(__fmul_rn(kBETA, ma), c), r2);
        float s1bv = (mb - kTHR > 0.f) ? 1.f : 0.f;
        mem1[idx] = mb; spk1[idx] = s1; spk1b[idx] = s1bv;
    }
    unsigned long long msk = __ballot(s1 > 0.5f);
    if ((threadIdx.x & 63) == 0) atomicAdd(cnt, (float)__popcll(msk));
}

// ---------------- generic spike GEMM with optional leaky epilogue ----------------
template <bool LEAKY, bool COUNT>
__global__ __launch_bounds__(256) void k_gemmL(
    const float* __restrict__ A, const float* __restrict__ W,
    const float* __restrict__ bias, float* __restrict__ mem,
    float* __restrict__ out, float* cnt, int K, int N, float beta, float thr)
{
    int b = blockIdx.y;
    int tid = threadIdx.x;
    int h = blockIdx.x * 256 + tid;
    __shared__ float a[1024];
    for (int j = tid; j < K; j += 256) a[j] = A[b * K + j];
    __syncthreads();
    float s = 0.f;
    if (h < N) {
        float acc0 = bias[h], acc1 = 0.f, acc2 = 0.f, acc3 = 0.f;
        const float* Wc = W + h;
        int j = 0;
        for (; j + 4 <= K; j += 4) {
            acc0 = fmaf(a[j],     Wc[(size_t)j * N],       acc0);
            acc1 = fmaf(a[j + 1], Wc[(size_t)(j + 1) * N], acc1);
            acc2 = fmaf(a[j + 2], Wc[(size_t)(j + 2) * N], acc2);
            acc3 = fmaf(a[j + 3], Wc[(size_t)(j + 3) * N], acc3);
        }
        for (; j < K; ++j) acc0 = fmaf(a[j], Wc[(size_t)j * N], acc0);
        float acc = (acc0 + acc1) + (acc2 + acc3);
        if (LEAKY) {
            float m = mem[b * N + h];
            float r = (m - thr > 0.f) ? thr : 0.f;
            float mn = __fsub_rn(__fadd_rn(__fmul_rn(beta, m), acc), r);
            mem[b * N + h] = mn;
            s = (mn - thr > 0.f) ? 1.f : 0.f;
            out[b * N + h] = s;
        } else {
            out[b * N + h] = acc;
        }
    }
    if (COUNT) {
        unsigned long long msk = __ballot(s > 0.5f);
        if ((tid & 63) == 0) atomicAdd(cnt, (float)__popcll(msk));
    }
}

// ---------------- fused k/v GEMM ----------------
__global__ __launch_bounds__(256) void k_gemm_kv(
    const float* __restrict__ spk3, const float* __restrict__ Wk,
    const float* __restrict__ bk, const float* __restrict__ Wv,
    const float* __restrict__ bv, float* __restrict__ kout, float* __restrict__ vout)
{
    int b = blockIdx.y;
    int tid = threadIdx.x;
    int h = blockIdx.x * 256 + tid;
    __shared__ float a[1000];
    for (int j = tid; j < 1000; j += 256) a[j] = spk3[b * 1000 + j];
    __syncthreads();
    if (h >= 1000) return;
    float ak = bk[h], av = bv[h];
    const float* kc = Wk + h;
    const float* vc = Wv + h;
    for (int j = 0; j < 1000; ++j) {
        float s = a[j];
        ak = fmaf(s, kc[(size_t)j * 1000], ak);
        av = fmaf(s, vc[(size_t)j * 1000], av);
    }
    kout[b * 1000 + h] = ak;
    vout[b * 1000 + h] = av;
}

// ---------------- RLeaky: rlin = spk1@WR+bR ; rec = spk_r@Vw ; update ----------------
__global__ __launch_bounds__(128) void k_rleaky(
    const float* __restrict__ spk1, const float* __restrict__ WR,
    const float* __restrict__ bR, const float* __restrict__ Vw,
    const float* __restrict__ Vb, float* __restrict__ mem_r,
    float* __restrict__ spk_r, float* cnt)
{
    int b = blockIdx.x;
    int tid = threadIdx.x;
    __shared__ float s1[1000];
    __shared__ float sr[100];
    for (int j = tid; j < 1000; j += 128) s1[j] = spk1[b * 1000 + j];
    if (tid < 100) sr[tid] = spk_r[b * 100 + tid];
    __syncthreads();
    float s = 0.f;
    float mn = 0.f;
    if (tid < 100) {
        float acc = bR[tid];
        for (int j = 0; j < 1000; ++j) acc = fmaf(s1[j], WR[j * 100 + tid], acc);
        float rec = 0.f;
        for (int j = 0; j < 100; ++j) rec = fmaf(sr[j], Vw[j * 100 + tid], rec);
        float m = mem_r[b * 100 + tid];
        float r = (m - kTHRR > 0.f) ? kTHRR : 0.f;
        mn = __fsub_rn(__fadd_rn(__fadd_rn(__fadd_rn(__fmul_rn(kBETAR, m), acc), rec), Vb[tid]), r);
        s = (mn - kTHRR > 0.f) ? 1.f : 0.f;
    }
    __syncthreads();   // all reads of old spk_r done before writes
    if (tid < 100) {
        mem_r[b * 100 + tid] = mn;
        spk_r[b * 100 + tid] = s;
    }
    unsigned long long msk = __ballot(s > 0.5f);
    if ((tid & 63) == 0) atomicAdd(cnt, (float)__popcll(msk));
}

// ---------------- attention: softmax_j(q_i*k_j/scale) . v ; partial dot with Wo ----------------
__global__ __launch_bounds__(128) void k_attn(
    const float* __restrict__ q, const float* __restrict__ kg,
    const float* __restrict__ vg, const float* __restrict__ Wo,
    float* __restrict__ part_att)
{
    int b = blockIdx.y;
    int it = blockIdx.x;
    int tid = threadIdx.x;
    __shared__ float kk[1000], vv[1000];
    __shared__ float rmax[128], rmin[128], rsum[128];
    float pmax = -3.4e38f, pmin = 3.4e38f;
    for (int j = tid; j < 1000; j += 128) {
        float kj = kg[b * 1000 + j];
        kk[j] = kj;
        vv[j] = vg[b * 1000 + j];
        pmax = fmaxf(pmax, kj);
        pmin = fminf(pmin, kj);
    }
    rmax[tid] = pmax; rmin[tid] = pmin;
    __syncthreads();
    for (int s2 = 64; s2 > 0; s2 >>= 1) {
        if (tid < s2) {
            rmax[tid] = fmaxf(rmax[tid], rmax[tid + s2]);
            rmin[tid] = fminf(rmin[tid], rmin[tid + s2]);
        }
        __syncthreads();
    }
    float kmax = rmax[0], kmin = rmin[0];
    float pw = 0.f;
    int i = it * 125 + tid;
    if (tid < 125) {
        float qi = q[b * 1000 + i];
        float qs = qi / 31.62277660168379f;   // sqrt(1000)
        float m = (qs >= 0.f) ? qs * kmax : qs * kmin;
        float den = 0.f, num = 0.f;
        for (int j = 0; j < 1000; ++j) {
            float e = __expf(fmaf(qs, kk[j], -m));
            den += e;
            num = fmaf(e, vv[j], num);
        }
        pw = (num / den) * Wo[i];
    }
    __syncthreads();
    rsum[tid] = pw;
    __syncthreads();
    for (int s2 = 64; s2 > 0; s2 >>= 1) {
        if (tid < s2) rsum[tid] += rsum[tid + s2];
        __syncthreads();
    }
    if (tid == 0) part_att[b * 8 + it] = rsum[0];
}

// ---------------- finalize: mem_out leaky, totals, reg, outputs ----------------
__global__ void k_final(const float* __restrict__ part_att, const float* __restrict__ bo,
                        float* __restrict__ mem_out, float* __restrict__ out_acc,
                        const float* __restrict__ cnt, float* __restrict__ sc,
                        float* __restrict__ dout, int t)
{
    int tid = threadIdx.x;   // 64 threads, one wave
    float s = 0.f;
    if (tid < 32) {
        float a = bo[0];
        for (int it = 0; it < 8; ++it) a += part_att[tid * 8 + it];
        float m = mem_out[tid];
        float r = (m - kTHR > 0.f) ? kTHR : 0.f;
        float mn = __fsub_rn(__fadd_rn(__fmul_rn(kBETA, m), a), r);
        mem_out[tid] = mn;
        s = (mn - kTHR > 0.f) ? 1.f : 0.f;
        float oa = out_acc[tid] + s;
        out_acc[tid] = oa;
        if (t == 4) dout[tid] = oa / 5.0f;
    }
    unsigned long long msk = __ballot(s > 0.5f);
    float co = (float)__popcll(msk);
    if (tid == 0) {
        float total = sc[0];
        float prev = total;
        total = __fadd_rn(total, __fdiv_rn(cnt[0], 32000.f));
        total = __fadd_rn(total, __fdiv_rn(cnt[1], 32000.f));
        total = __fadd_rn(total, __fdiv_rn(cnt[2], 3200.f));
        total = __fadd_rn(total, __fdiv_rn(co, 32.f));
        float reg = sc[1];
        reg = __fadd_rn(reg, __fmul_rn(kLM, total));
        if (t > 0) reg = __fadd_rn(reg, __fmul_rn(kLM, fabsf(__fsub_rn(total, prev))));
        sc[0] = total; sc[1] = reg;
        if (t == 4) dout[32] = reg / 5.0f;
    }
}

// ---------------- host ----------------
extern "C" void kernel_launch(void* const* d_in, const int* in_sizes, int n_in,
                              void* d_out, int out_size, void* d_ws, size_t ws_size,
                              hipStream_t stream)
{
    const float* data = (const float*)d_in[0];
    const float* Wpe  = (const float*)d_in[1];
    const float* bpe  = (const float*)d_in[2];
    const float* pos  = (const float*)d_in[3];
    const float* W1   = (const float*)d_in[4];
    const float* b1   = (const float*)d_in[5];
    const float* W2   = (const float*)d_in[6];
    const float* b2   = (const float*)d_in[7];
    const float* W3   = (const float*)d_in[8];
    const float* b3   = (const float*)d_in[9];
    const float* WR   = (const float*)d_in[10];
    const float* bR   = (const float*)d_in[11];
    const float* Vw   = (const float*)d_in[12];
    const float* Vb   = (const float*)d_in[13];
    const float* Wq   = (const float*)d_in[14];
    const float* bq   = (const float*)d_in[15];
    const float* Wk   = (const float*)d_in[16];
    const float* bk   = (const float*)d_in[17];
    const float* Wv   = (const float*)d_in[18];
    const float* bv   = (const float*)d_in[19];
    const float* Wo   = (const float*)d_in[20];
    const float* bo   = (const float*)d_in[21];

    float* ws = (float*)d_ws;
    float* dout = (float*)d_out;

    float* xf    = ws + OFF_X;
    float* cur1  = ws + OFF_CUR1;
    float* mem1  = ws + OFF_MEM1;
    float* mem2  = ws + OFF_MEM2;
    float* mem3  = ws + OFF_MEM3;
    float* spk1  = ws + OFF_SPK1;
    float* spk1b = ws + OFF_SPK1B;
    float* spk2  = ws + OFF_SPK2;
    float* spk3  = ws + OFF_SPK3;
    float* qb    = ws + OFF_Q;
    float* kb    = ws + OFF_K;
    float* vb    = ws + OFF_V;
    float* memr  = ws + OFF_MEMR;
    float* spkr  = ws + OFF_SPKR;
    float* memo  = ws + OFF_MEMO;
    float* patt  = ws + OFF_PATT;
    float* cntb  = ws + OFF_CNT;
    float* oacc  = ws + OFF_OACC;
    float* sc    = ws + OFF_SC;
    float* part  = ws + OFF_PART;

    // chunk count for the big GEMM, sized from available workspace.
    // cap 365 (tpc=2): 365 chunks x 2 batch-groups = 730 blocks
    // ~= 11.4 waves/CU (was 243x1 blocks = 3.8 waves/CU, 10.7% occupancy).
    size_t ws_f = ws_size / 4;
    size_t avail = (ws_f > OFF_PART) ? (ws_f - OFF_PART) : 0;
    long nchunk_l = (long)(avail / 32000);
    int nchunk = (nchunk_l > 365) ? 365 : (int)nchunk_l;
    if (nchunk < 1) nchunk = 1;
    int tpc = (729 + nchunk - 1) / nchunk;
    nchunk = (729 + tpc - 1) / tpc;

    k_init<<<402, 256, 0, stream>>>(ws);
    k_patch<<<23328, 64, 0, stream>>>(data, Wpe, bpe, pos, xf);
    k_gemm1_part<<<dim3(nchunk, 2), 256, 0, stream>>>(xf, W1, part, tpc);
    k_gemm1_reduce<<<125, 256, 0, stream>>>(part, b1, cur1, nchunk);

    for (int t = 0; t < 5; ++t) {
        float* cnt = cntb + t * 4;
        k_stepA<<<125, 256, 0, stream>>>(cur1, mem1, spk1, spk1b, cnt + 0);
        k_gemmL<true, false><<<dim3(4, 32), 256, 0, stream>>>(
            spk1b, W2, b2, mem2, spk2, nullptr, 1000, 1000, kBETA, kTHR);
        k_gemmL<true, true><<<dim3(4, 32), 256, 0, stream>>>(
            spk2, W3, b3, mem3, spk3, cnt + 1, 1000, 1000, kBETA, kTHR);
        k_rleaky<<<32, 128, 0, stream>>>(spk1, WR, bR, Vw, Vb, memr, spkr, cnt + 2);
        k_gemmL<false, false><<<dim3(4, 32), 256, 0, stream>>>(
            spkr, Wq, bq, nullptr, qb, nullptr, 100, 1000, 0.f, 0.f);
        k_gemm_kv<<<dim3(4, 32), 256, 0, stream>>>(spk3, Wk, bk, Wv, bv, kb, vb);
        k_attn<<<dim3(8, 32), 128, 0, stream>>>(qb, kb, vb, Wo, patt);
        k_final<<<1, 64, 0, stream>>>(patt, bo, memo, oacc, cnt, sc, dout, t);
    }
    (void)in_sizes; (void)n_in; (void)out_size;
}

// Round 2
// 829.865 us; speedup vs baseline: 1.5867x; 1.5867x over previous
//
#include <hip/hip_runtime.h>

// ---------------- workspace layout (float offsets) ----------------
#define OFF_X     0          // x_flat [32][46656]
#define OFF_CUR1  1492992    // [32][1000]
#define OFF_MEM1  1524992
#define OFF_MEM2  1556992
#define OFF_MEM3  1588992
#define OFF_SPK1  1620992
#define OFF_SPK1B 1652992
#define OFF_SPK2  1684992
#define OFF_SPK3  1716992
#define OFF_Q     1748992    // (unused now, q fused into attn)
#define OFF_K     1780992
#define OFF_V     1812992
#define OFF_MEMR  1844992    // [32][100]
#define OFF_SPKR  1848192    // [32][100]
#define OFF_MEMO  1851392    // [32]
#define OFF_PATT  1851424    // [32][8] attention partial sums
#define OFF_CNT   1851680    // [5][4] spike counters
#define OFF_OACC  1851700    // [32]
#define OFF_SC    1851732    // total, reg
#define OFF_PART  1851744    // gemm1 partials [nchunk][32][1000]; later step partials

// step-GEMM split-K partials (reuse the PART region after gemm1_reduce)
#define OFF_PARTG  OFF_PART              // [25][32][1000]
#define OFF_PARTK  (OFF_PART + 800000)   // [25][32][1000]
#define OFF_PARTV  (OFF_PART + 1600000)  // [25][32][1000]

#define KC    25   // K-chunks for step GEMMs
#define CHUNK 40   // 25*40 = 1000

static constexpr float kBETA  = 0.8f;
static constexpr float kTHR   = 0.5f;
static constexpr float kBETAR = 0.95f;
static constexpr float kTHRR  = 1.0f;
static constexpr float kLM    = 0.0058f;

// ---------------- init: zero all persistent state ----------------
__global__ void k_init(float* ws) {
    int idx = blockIdx.x * 256 + threadIdx.x;
    if (idx < 96000) {
        ws[OFF_MEM1 + idx] = 0.f;                 // mem1, mem2, mem3 (contiguous)
    } else {
        int j = idx - 96000;
        if (j < 6744) ws[OFF_MEMR + j] = 0.f;     // mem_r..sc (contiguous)
    }
}

// ---------------- patch embed: x = patches @ W_pe + b_pe + pos ----------------
__global__ __launch_bounds__(64) void k_patch(
    const float* __restrict__ data, const float* __restrict__ Wpe,
    const float* __restrict__ bpe, const float* __restrict__ pos,
    float* __restrict__ xf)
{
    int bp = blockIdx.x;
    int b = bp / 729, p = bp % 729;
    int pr = p / 27, pc = p % 27;
    int tid = threadIdx.x;
    __shared__ float patch[256];
    const float* db = data + (size_t)b * 50176;
    for (int c = tid; c < 256; c += 64) {
        int ph = c >> 4, pw = c & 15;
        patch[c] = db[(pr * 8 + ph) * 224 + pc * 8 + pw];
    }
    __syncthreads();
    float acc = bpe[tid] + pos[p * 64 + tid];
    for (int c = 0; c < 256; ++c)
        acc = fmaf(patch[c], Wpe[c * 64 + tid], acc);
    xf[(size_t)b * 46656 + p * 64 + tid] = acc;
}

// ---------------- big GEMM partials: cur1 += x_flat @ W1 (chunked over K) ----------------
__global__ __launch_bounds__(256) void k_gemm1_part(
    const float* __restrict__ xf, const float* __restrict__ W1,
    float* __restrict__ part, int tpc)
{
    int chunk = blockIdx.x;
    int bg = blockIdx.y;                 // batch group: batches [bg*16, bg*16+16)
    int t0 = chunk * tpc;
    int t1 = t0 + tpc; if (t1 > 729) t1 = 729;
    int tid = threadIdx.x;
    __shared__ float xs[1024];           // [16 b][64 i]
    float acc[16][4];
    #pragma unroll
    for (int b = 0; b < 16; ++b)
        #pragma unroll
        for (int j = 0; j < 4; ++j) acc[b][j] = 0.f;

    const size_t bbase = (size_t)(bg * 16) * 46656;
    for (int tt = t0; tt < t1; ++tt) {
        int i0 = tt * 64;
        __syncthreads();
        for (int l = tid; l < 1024; l += 256)
            xs[l] = xf[bbase + (size_t)(l >> 6) * 46656 + i0 + (l & 63)];
        __syncthreads();
        for (int ii4 = 0; ii4 < 16; ++ii4) {
            int i = i0 + ii4 * 4;
            float w0[4], w1v[4], w2[4], w3[4];
            #pragma unroll
            for (int j = 0; j < 4; ++j) {
                int h = tid + j * 256;
                bool ok = h < 1000;
                const float* col = W1 + (size_t)i * 1000 + (ok ? h : 0);
                w0[j]  = ok ? col[0]    : 0.f;
                w1v[j] = ok ? col[1000] : 0.f;
                w2[j]  = ok ? col[2000] : 0.f;
                w3[j]  = ok ? col[3000] : 0.f;
            }
            #pragma unroll
            for (int b = 0; b < 16; ++b) {
                float4 xv = *reinterpret_cast<const float4*>(&xs[b * 64 + ii4 * 4]);
                #pragma unroll
                for (int j = 0; j < 4; ++j) {
                    float a = acc[b][j];
                    a = fmaf(xv.x, w0[j],  a);
                    a = fmaf(xv.y, w1v[j], a);
                    a = fmaf(xv.z, w2[j],  a);
                    a = fmaf(xv.w, w3[j],  a);
                    acc[b][j] = a;
                }
            }
        }
    }
    float* pc = part + (size_t)chunk * 32000 + (size_t)(bg * 16) * 1000;
    for (int b = 0; b < 16; ++b)
        #pragma unroll
        for (int j = 0; j < 4; ++j) {
            int h = tid + j * 256;
            if (h < 1000) pc[b * 1000 + h] = acc[b][j];
        }
}

__global__ void k_gemm1_reduce(const float* __restrict__ part,
                               const float* __restrict__ b1,
                               float* __restrict__ cur1, int nchunk)
{
    int idx = blockIdx.x * 256 + threadIdx.x;
    if (idx >= 32000) return;
    int h = idx % 1000;
    float a = b1[h];
    for (int c = 0; c < nchunk; ++c) a += part[(size_t)c * 32000 + idx];
    cur1[idx] = a;
}

// ---------------- step A: double leaky on mem1 ----------------
__global__ void k_stepA(const float* __restrict__ cur1, float* __restrict__ mem1,
                        float* __restrict__ spk1, float* __restrict__ spk1b, float* cnt)
{
    int idx = blockIdx.x * 256 + threadIdx.x;
    float s1 = 0.f;
    if (idx < 32000) {
        float m = mem1[idx], c = cur1[idx];
        float r1 = (m - kTHR > 0.f) ? kTHR : 0.f;
        float ma = __fsub_rn(__fadd_rn(__fmul_rn(kBETA, m), c), r1);
        s1 = (ma - kTHR > 0.f) ? 1.f : 0.f;
        float r2 = __fmul_rn(s1, kTHR);
        float mb = __fsub_rn(__fadd_rn(__fmul_rn(kBETA, ma), c), r2);
        float s1bv = (mb - kTHR > 0.f) ? 1.f : 0.f;
        mem1[idx] = mb; spk1[idx] = s1; spk1b[idx] = s1bv;
    }
    unsigned long long msk = __ballot(s1 > 0.5f);
    if ((threadIdx.x & 63) == 0) atomicAdd(cnt, (float)__popcll(msk));
}

// ---------------- split-K spike-GEMM partial: part[kc] = A-chunk @ W-chunk ----------------
// grid (8 hblk x KC kchunk), 128 threads; thread owns 1 h column, acc over all 32 batches.
// A chunk staged in LDS as [jj][32] so inner loop reads 8x float4 broadcasts (no conflicts).
__global__ __launch_bounds__(128) void k_gsp(
    const float* __restrict__ A, const float* __restrict__ W,
    float* __restrict__ part)
{
    int hb = blockIdx.x, kc = blockIdx.y, tid = threadIdx.x;
    int j0 = kc * CHUNK;
    __shared__ __align__(16) float al[CHUNK * 32];
    for (int l = tid; l < CHUNK * 32; l += 128)
        al[l] = A[(size_t)(l & 31) * 1000 + j0 + (l >> 5)];
    __syncthreads();
    if (tid >= 125) return;
    int h = hb * 125 + tid;
    float acc[32];
    #pragma unroll
    for (int b = 0; b < 32; ++b) acc[b] = 0.f;
    const float* Wp = W + (size_t)j0 * 1000 + h;
    #pragma unroll 2
    for (int jj = 0; jj < CHUNK; ++jj) {
        float w = Wp[(size_t)jj * 1000];
        const float4* a4 = reinterpret_cast<const float4*>(&al[jj * 32]);
        #pragma unroll
        for (int q = 0; q < 8; ++q) {
            float4 av = a4[q];
            acc[q * 4 + 0] = fmaf(av.x, w, acc[q * 4 + 0]);
            acc[q * 4 + 1] = fmaf(av.y, w, acc[q * 4 + 1]);
            acc[q * 4 + 2] = fmaf(av.z, w, acc[q * 4 + 2]);
            acc[q * 4 + 3] = fmaf(av.w, w, acc[q * 4 + 3]);
        }
    }
    float* pp = part + (size_t)kc * 32000 + h;
    #pragma unroll
    for (int b = 0; b < 32; ++b) pp[(size_t)b * 1000] = acc[b];
}

// dual-weight variant for k/v
__global__ __launch_bounds__(128) void k_gsp_kv(
    const float* __restrict__ A, const float* __restrict__ Wk,
    const float* __restrict__ Wv, float* __restrict__ pk, float* __restrict__ pv)
{
    int hb = blockIdx.x, kc = blockIdx.y, tid = threadIdx.x;
    int j0 = kc * CHUNK;
    __shared__ __align__(16) float al[CHUNK * 32];
    for (int l = tid; l < CHUNK * 32; l += 128)
        al[l] = A[(size_t)(l & 31) * 1000 + j0 + (l >> 5)];
    __syncthreads();
    if (tid >= 125) return;
    int h = hb * 125 + tid;
    float acck[32], accv[32];
    #pragma unroll
    for (int b = 0; b < 32; ++b) { acck[b] = 0.f; accv[b] = 0.f; }
    const float* Wkp = Wk + (size_t)j0 * 1000 + h;
    const float* Wvp = Wv + (size_t)j0 * 1000 + h;
    #pragma unroll 2
    for (int jj = 0; jj < CHUNK; ++jj) {
        float wk = Wkp[(size_t)jj * 1000];
        float wv = Wvp[(size_t)jj * 1000];
        const float4* a4 = reinterpret_cast<const float4*>(&al[jj * 32]);
        #pragma unroll
        for (int q = 0; q < 8; ++q) {
            float4 av = a4[q];
            acck[q * 4 + 0] = fmaf(av.x, wk, acck[q * 4 + 0]);
            acck[q * 4 + 1] = fmaf(av.y, wk, acck[q * 4 + 1]);
            acck[q * 4 + 2] = fmaf(av.z, wk, acck[q * 4 + 2]);
            acck[q * 4 + 3] = fmaf(av.w, wk, acck[q * 4 + 3]);
            accv[q * 4 + 0] = fmaf(av.x, wv, accv[q * 4 + 0]);
            accv[q * 4 + 1] = fmaf(av.y, wv, accv[q * 4 + 1]);
            accv[q * 4 + 2] = fmaf(av.z, wv, accv[q * 4 + 2]);
            accv[q * 4 + 3] = fmaf(av.w, wv, accv[q * 4 + 3]);
        }
    }
    float* ppk = pk + (size_t)kc * 32000 + h;
    float* ppv = pv + (size_t)kc * 32000 + h;
    #pragma unroll
    for (int b = 0; b < 32; ++b) {
        ppk[(size_t)b * 1000] = acck[b];
        ppv[(size_t)b * 1000] = accv[b];
    }
}

// ---------------- reduce partials + leaky epilogue ----------------
template <bool COUNT>
__global__ __launch_bounds__(256) void k_gred(
    const float* __restrict__ part, const float* __restrict__ bias,
    float* __restrict__ mem, float* __restrict__ spk, float* cnt,
    float beta, float thr)
{
    int idx = blockIdx.x * 256 + threadIdx.x;
    float s = 0.f;
    if (idx < 32000) {
        int h = idx % 1000;
        float a = bias[h];
        for (int c = 0; c < KC; ++c) a += part[(size_t)c * 32000 + idx];
        float m = mem[idx];
        float r = (m - thr > 0.f) ? thr : 0.f;
        float mn = __fsub_rn(__fadd_rn(__fmul_rn(beta, m), a), r);
        mem[idx] = mn;
        s = (mn - thr > 0.f) ? 1.f : 0.f;
        spk[idx] = s;
    }
    if (COUNT) {
        unsigned long long msk = __ballot(s > 0.5f);
        if ((threadIdx.x & 63) == 0) atomicAdd(cnt, (float)__popcll(msk));
    }
}

__global__ __launch_bounds__(256) void k_gred_kv(
    const float* __restrict__ pk, const float* __restrict__ pv,
    const float* __restrict__ bk, const float* __restrict__ bv,
    float* __restrict__ ko, float* __restrict__ vo)
{
    int idx = blockIdx.x * 256 + threadIdx.x;
    if (idx >= 32000) return;
    int h = idx % 1000;
    float ak = bk[h], av = bv[h];
    for (int c = 0; c < KC; ++c) {
        ak += pk[(size_t)c * 32000 + idx];
        av += pv[(size_t)c * 32000 + idx];
    }
    ko[idx] = ak;
    vo[idx] = av;
}

// ---------------- RLeaky: rlin = spk1@WR+bR ; rec = spk_r@Vw ; update ----------------
__global__ __launch_bounds__(128) void k_rleaky(
    const float* __restrict__ spk1, const float* __restrict__ WR,
    const float* __restrict__ bR, const float* __restrict__ Vw,
    const float* __restrict__ Vb, float* __restrict__ mem_r,
    float* __restrict__ spk_r, float* cnt)
{
    int b = blockIdx.x;
    int tid = threadIdx.x;
    __shared__ float s1[1000];
    __shared__ float sr[100];
    for (int j = tid; j < 1000; j += 128) s1[j] = spk1[b * 1000 + j];
    if (tid < 100) sr[tid] = spk_r[b * 100 + tid];
    __syncthreads();
    float s = 0.f;
    float mn = 0.f;
    if (tid < 100) {
        float acc = bR[tid];
        for (int j = 0; j < 1000; ++j) acc = fmaf(s1[j], WR[j * 100 + tid], acc);
        float rec = 0.f;
        for (int j = 0; j < 100; ++j) rec = fmaf(sr[j], Vw[j * 100 + tid], rec);
        float m = mem_r[b * 100 + tid];
        float r = (m - kTHRR > 0.f) ? kTHRR : 0.f;
        mn = __fsub_rn(__fadd_rn(__fadd_rn(__fadd_rn(__fmul_rn(kBETAR, m), acc), rec), Vb[tid]), r);
        s = (mn - kTHRR > 0.f) ? 1.f : 0.f;
    }
    __syncthreads();   // all reads of old spk_r done before writes
    if (tid < 100) {
        mem_r[b * 100 + tid] = mn;
        spk_r[b * 100 + tid] = s;
    }
    unsigned long long msk = __ballot(s > 0.5f);
    if ((tid & 63) == 0) atomicAdd(cnt, (float)__popcll(msk));
}

// ---------------- attention (q fused): q_i = spkr@Wq+bq; softmax_j(q_i*k_j/scale).v ----------------
__global__ __launch_bounds__(128) void k_attn(
    const float* __restrict__ spkr, const float* __restrict__ Wq,
    const float* __restrict__ bq, const float* __restrict__ kg,
    const float* __restrict__ vg, const float* __restrict__ Wo,
    float* __restrict__ part_att)
{
    int b = blockIdx.y;
    int it = blockIdx.x;
    int tid = threadIdx.x;
    __shared__ float kk[1000], vv[1000];
    __shared__ float sr[100];
    __shared__ float rmax[128], rmin[128], rsum[128];
    float pmax = -3.4e38f, pmin = 3.4e38f;
    if (tid < 100) sr[tid] = spkr[b * 100 + tid];
    for (int j = tid; j < 1000; j += 128) {
        float kj = kg[b * 1000 + j];
        kk[j] = kj;
        vv[j] = vg[b * 1000 + j];
        pmax = fmaxf(pmax, kj);
        pmin = fminf(pmin, kj);
    }
    rmax[tid] = pmax; rmin[tid] = pmin;
    __syncthreads();
    for (int s2 = 64; s2 > 0; s2 >>= 1) {
        if (tid < s2) {
            rmax[tid] = fmaxf(rmax[tid], rmax[tid + s2]);
            rmin[tid] = fminf(rmin[tid], rmin[tid + s2]);
        }
        __syncthreads();
    }
    float kmax = rmax[0], kmin = rmin[0];
    float pw = 0.f;
    int i = it * 125 + tid;
    if (tid < 125) {
        float qi = bq[i];
        for (int j = 0; j < 100; ++j) qi = fmaf(sr[j], Wq[j * 1000 + i], qi);
        float qs = qi / 31.62277660168379f;   // sqrt(1000)
        float m = (qs >= 0.f) ? qs * kmax : qs * kmin;
        float den = 0.f, num = 0.f;
        for (int j = 0; j < 1000; ++j) {
            float e = __expf(fmaf(qs, kk[j], -m));
            den += e;
            num = fmaf(e, vv[j], num);
        }
        pw = (num / den) * Wo[i];
    }
    __syncthreads();
    rsum[tid] = pw;
    __syncthreads();
    for (int s2 = 64; s2 > 0; s2 >>= 1) {
        if (tid < s2) rsum[tid] += rsum[tid + s2];
        __syncthreads();
    }
    if (tid == 0) part_att[b * 8 + it] = rsum[0];
}

// ---------------- finalize: mem_out leaky, totals, reg, outputs ----------------
__global__ void k_final(const float* __restrict__ part_att, const float* __restrict__ bo,
                        float* __restrict__ mem_out, float* __restrict__ out_acc,
                        const float* __restrict__ cnt, float* __restrict__ sc,
                        float* __restrict__ dout, int t)
{
    int tid = threadIdx.x;   // 64 threads, one wave
    float s = 0.f;
    if (tid < 32) {
        float a = bo[0];
        for (int it = 0; it < 8; ++it) a += part_att[tid * 8 + it];
        float m = mem_out[tid];
        float r = (m - kTHR > 0.f) ? kTHR : 0.f;
        float mn = __fsub_rn(__fadd_rn(__fmul_rn(kBETA, m), a), r);
        mem_out[tid] = mn;
        s = (mn - kTHR > 0.f) ? 1.f : 0.f;
        float oa = out_acc[tid] + s;
        out_acc[tid] = oa;
        if (t == 4) dout[tid] = oa / 5.0f;
    }
    unsigned long long msk = __ballot(s > 0.5f);
    float co = (float)__popcll(msk);
    if (tid == 0) {
        float total = sc[0];
        float prev = total;
        total = __fadd_rn(total, __fdiv_rn(cnt[0], 32000.f));
        total = __fadd_rn(total, __fdiv_rn(cnt[1], 32000.f));
        total = __fadd_rn(total, __fdiv_rn(cnt[2], 3200.f));
        total = __fadd_rn(total, __fdiv_rn(co, 32.f));
        float reg = sc[1];
        reg = __fadd_rn(reg, __fmul_rn(kLM, total));
        if (t > 0) reg = __fadd_rn(reg, __fmul_rn(kLM, fabsf(__fsub_rn(total, prev))));
        sc[0] = total; sc[1] = reg;
        if (t == 4) dout[32] = reg / 5.0f;
    }
}

// ---------------- host ----------------
extern "C" void kernel_launch(void* const* d_in, const int* in_sizes, int n_in,
                              void* d_out, int out_size, void* d_ws, size_t ws_size,
                              hipStream_t stream)
{
    const float* data = (const float*)d_in[0];
    const float* Wpe  = (const float*)d_in[1];
    const float* bpe  = (const float*)d_in[2];
    const float* pos  = (const float*)d_in[3];
    const float* W1   = (const float*)d_in[4];
    const float* b1   = (const float*)d_in[5];
    const float* W2   = (const float*)d_in[6];
    const float* b2   = (const float*)d_in[7];
    const float* W3   = (const float*)d_in[8];
    const float* b3   = (const float*)d_in[9];
    const float* WR   = (const float*)d_in[10];
    const float* bR   = (const float*)d_in[11];
    const float* Vw   = (const float*)d_in[12];
    const float* Vb   = (const float*)d_in[13];
    const float* Wq   = (const float*)d_in[14];
    const float* bq   = (const float*)d_in[15];
    const float* Wk   = (const float*)d_in[16];
    const float* bk   = (const float*)d_in[17];
    const float* Wv   = (const float*)d_in[18];
    const float* bv   = (const float*)d_in[19];
    const float* Wo   = (const float*)d_in[20];
    const float* bo   = (const float*)d_in[21];

    float* ws = (float*)d_ws;
    float* dout = (float*)d_out;

    float* xf    = ws + OFF_X;
    float* cur1  = ws + OFF_CUR1;
    float* mem1  = ws + OFF_MEM1;
    float* mem2  = ws + OFF_MEM2;
    float* mem3  = ws + OFF_MEM3;
    float* spk1  = ws + OFF_SPK1;
    float* spk1b = ws + OFF_SPK1B;
    float* spk2  = ws + OFF_SPK2;
    float* spk3  = ws + OFF_SPK3;
    float* kb_   = ws + OFF_K;
    float* vb_   = ws + OFF_V;
    float* memr  = ws + OFF_MEMR;
    float* spkr  = ws + OFF_SPKR;
    float* memo  = ws + OFF_MEMO;
    float* patt  = ws + OFF_PATT;
    float* cntb  = ws + OFF_CNT;
    float* oacc  = ws + OFF_OACC;
    float* sc    = ws + OFF_SC;
    float* part  = ws + OFF_PART;
    float* partg = ws + OFF_PARTG;
    float* partk = ws + OFF_PARTK;
    float* partv = ws + OFF_PARTV;

    // chunk count for the big GEMM, sized from available workspace.
    size_t ws_f = ws_size / 4;
    size_t avail = (ws_f > OFF_PART) ? (ws_f - OFF_PART) : 0;
    long nchunk_l = (long)(avail / 32000);
    int nchunk = (nchunk_l > 365) ? 365 : (int)nchunk_l;
    if (nchunk < 1) nchunk = 1;
    int tpc = (729 + nchunk - 1) / nchunk;
    nchunk = (729 + tpc - 1) / tpc;

    k_init<<<402, 256, 0, stream>>>(ws);
    k_patch<<<23328, 64, 0, stream>>>(data, Wpe, bpe, pos, xf);
    k_gemm1_part<<<dim3(nchunk, 2), 256, 0, stream>>>(xf, W1, part, tpc);
    k_gemm1_reduce<<<125, 256, 0, stream>>>(part, b1, cur1, nchunk);

    for (int t = 0; t < 5; ++t) {
        float* cnt = cntb + t * 4;
        k_stepA<<<125, 256, 0, stream>>>(cur1, mem1, spk1, spk1b, cnt + 0);
        k_rleaky<<<32, 128, 0, stream>>>(spk1, WR, bR, Vw, Vb, memr, spkr, cnt + 2);
        // layer 2: spk1b @ W2 -> leaky -> spk2
        k_gsp<<<dim3(8, KC), 128, 0, stream>>>(spk1b, W2, partg);
        k_gred<false><<<125, 256, 0, stream>>>(partg, b2, mem2, spk2, nullptr, kBETA, kTHR);
        // layer 3: spk2 @ W3 -> leaky -> spk3 (+count)
        k_gsp<<<dim3(8, KC), 128, 0, stream>>>(spk2, W3, partg);
        k_gred<true><<<125, 256, 0, stream>>>(partg, b3, mem3, spk3, cnt + 1, kBETA, kTHR);
        // k/v: spk3 @ Wk, Wv
        k_gsp_kv<<<dim3(8, KC), 128, 0, stream>>>(spk3, Wk, Wv, partk, partv);
        k_gred_kv<<<125, 256, 0, stream>>>(partk, partv, bk, bv, kb_, vb_);
        // attention with fused q-GEMM
        k_attn<<<dim3(8, 32), 128, 0, stream>>>(spkr, Wq, bq, kb_, vb_, Wo, patt);
        k_final<<<1, 64, 0, stream>>>(patt, bo, memo, oacc, cnt, sc, dout, t);
    }
    (void)in_sizes; (void)n_in; (void)out_size;
}